// Round 15
// baseline (91.304 us; speedup 1.0000x reference)
//
#include <hip/hip_runtime.h>

// Per-element MLP 1->32->(32x32)x9->1, leaky relu, v_mfma_f32_16x16x32_f16.
// R20: balanced point of the two measured walls. R19 (NCHAIN=1, 8 w/SIMD)
// ran ~36us steady: its 48 LDS-b128/32-elems costs ~31us of CU LDS pipe --
// it swapped R14's latency wall (NCHAIN=6, 2 w/SIMD, ~5us LDS, 41.8us)
// for an equal-height LDS-throughput wall. All prior configs sat at one
// extreme. Interior point: NCHAIN=4 x 4 waves/SIMD -> LDS ~8us/CU AND
// latency coverage ~4x45%~180%. Register plan (R6 spill trap avoided):
// SEQUENTIAL acc groups of 2 chains (32 acc regs peak, not 64), io
// fragments in LDS, no rotation -> ~104 regs, 24 slack under (256,4)=128.
// grid 1024 = 4 blocks/CU (LDS 19.3KiB x4 = 77KiB), niter 8192 = exactly
// 2 iters/wave. N%128==0 -> no tail checks.
// Gate: WRITE_SIZE ~4MB (no spill), VGPR<=128. Predict steady 22-30us,
// harness 78-88; flat >=90 => both walls simultaneous, declare plateau.
#define NLAYERS 9
#define HID 32
#define SLOPE 0.01f

typedef _Float16 v2h __attribute__((ext_vector_type(2)));
typedef _Float16 v8h __attribute__((ext_vector_type(8)));
typedef float v4f __attribute__((ext_vector_type(4)));

#define NCHAIN 4

union U8 { v8h v; v2h p[4]; };          // B-operand fragment (8 f16 = 4 VGPRs)

__device__ __forceinline__ v2h pk_cvt(float a, float b) {
    return __builtin_bit_cast(v2h, __builtin_amdgcn_cvt_pkrtz(a, b));
}
__device__ __forceinline__ v2h leaky2(v2h t, v2h s) {
    return __builtin_elementwise_max(t, t * s);
}
// k-slot (group g = lane>>4, elem j) -> logical hidden unit; derived from the
// verified 16x16 C/D layout so epilogue pk pairs feed the next B directly
// (validated numerically in R10/R14/R17/R19).
__device__ __forceinline__ int umap(int g, int j) {
    return 4 * g + (j & 3) + 16 * (j >> 2);
}

__global__ __launch_bounds__(256, 4) void mlp_mfma_kernel(
    const float* __restrict__ x,
    const float* __restrict__ W_in,   // [1,32]
    const float* __restrict__ b_in,   // [32]
    const float* __restrict__ W_hid,  // [9,32,32]  W[l][k_in][n_out]
    const float* __restrict__ b_hid,  // [9,32]
    const float* __restrict__ W_out,  // [32,1]
    const float* __restrict__ b_out,  // [1]
    float* __restrict__ out, int N)
{
    // A-operand fragments, pre-permuted: lane ln=(i | g<<4) of tile t reads
    // 16B contiguous = W[umap(g,j)][16t+i], j=0..7. 64x16B = conflict-free.
    __shared__ __align__(16) _Float16 wA_sh[NLAYERS][2][64][8];  // 18 KiB
    // f32 bias in 16x16 C layout: tile t, entry 4g+r <- b_hid[16t+4g+r]
    __shared__ __align__(64) float bc_sh[NLAYERS][2][16];        // 1.1 KiB
    // io-layer fragments, indexed by k-group g (b128 broadcast reads)
    __shared__ __align__(16) v2h win_sh[4][4], bin_sh[4][4], wout_sh[4][4];

    const int tid = threadIdx.x;
    for (int t = tid; t < NLAYERS * 2 * 64; t += blockDim.x) {
        int l = t >> 7, r = t & 127, tt = (r >> 6) & 1, ln = r & 63;
        int i = ln & 15, gg = ln >> 4;
        const float* Wl = W_hid + l * HID * HID;
        v8h w;
#pragma unroll
        for (int j = 0; j < 8; ++j)
            w[j] = (_Float16)Wl[umap(gg, j) * HID + 16 * tt + i];
        *(v8h*)&wA_sh[l][tt][ln][0] = w;
    }
    for (int t = tid; t < NLAYERS * HID; t += blockDim.x)
        ((float*)bc_sh)[t] = b_hid[t];   // flat layout matches b_hid exactly
    if (tid < 16) {
        int gg = tid >> 2, jj = tid & 3;
        int u0 = umap(gg, 2 * jj), u1 = umap(gg, 2 * jj + 1);  // u1 == u0+1
        win_sh[gg][jj]  = v2h{(_Float16)W_in[u0],  (_Float16)W_in[u1]};
        bin_sh[gg][jj]  = v2h{(_Float16)b_in[u0],  (_Float16)b_in[u1]};
        wout_sh[gg][jj] = v2h{(_Float16)W_out[u0], (_Float16)W_out[u1]};
    }
    __syncthreads();

    const int lane = tid & 63;
    const int g    = lane >> 4;     // k-group / C-row group
    const int col  = lane & 15;     // batch column within 16-wide half

    const float bo = b_out[0];
    const v2h slope2 = v2h{(_Float16)SLOPE, (_Float16)SLOPE};

    const int nwaves = (gridDim.x * blockDim.x) >> 6;
    const int wid    = ((blockIdx.x * blockDim.x) >> 6) + (tid >> 6);
    const int niter  = N / (NCHAIN * 32);   // N % 128 == 0: no tail

    // ---- x prefetch for first iteration, packed f16 (2 cols/lane/chain) ----
    v2h xc2[NCHAIN];
#pragma unroll
    for (int c = 0; c < NCHAIN; ++c) xc2[c] = v2h{(_Float16)0.f, (_Float16)0.f};
    if (wid < niter) {
#pragma unroll
        for (int c = 0; c < NCHAIN; ++c) {
            int i0 = wid * (NCHAIN * 32) + c * 32 + col;
            xc2[c] = pk_cvt(x[i0], x[i0 + 16]);
        }
    }

    for (int it = wid; it < niter; it += nwaves) {
        // prefetch next iteration's x (hides HBM latency under compute)
        v2h xn2[NCHAIN];
#pragma unroll
        for (int c = 0; c < NCHAIN; ++c) xn2[c] = v2h{(_Float16)0.f, (_Float16)0.f};
        {
            int nit = it + nwaves;
            if (nit < niter) {
#pragma unroll
                for (int c = 0; c < NCHAIN; ++c) {
                    int i0 = nit * (NCHAIN * 32) + c * 32 + col;
                    xn2[c] = pk_cvt(x[i0], x[i0 + 16]);
                }
            }
        }

        // ---- input layer: build B fragments for all chains/halves ----
        U8 f[NCHAIN][2];
        {
            const v2h* wi = &win_sh[g][0];
            const v2h* bi = &bin_sh[g][0];
#pragma unroll
            for (int c = 0; c < NCHAIN; ++c)
#pragma unroll
                for (int nh = 0; nh < 2; ++nh) {
                    v2h x2 = v2h{xc2[c][nh], xc2[c][nh]};
#pragma unroll
                    for (int jj = 0; jj < 4; ++jj)
                        f[c][nh].p[jj] = leaky2(x2 * wi[jj] + bi[jj], slope2);
                }
        }

        // ---- 9 hidden layers: rolled loop (R9 spill fix); SEQUENTIAL
        // 2-chain acc groups (32 acc regs peak); cross-group/wave overlap
        // covers latency at 4 waves/SIMD; LDS reads amortized over 128 elems.
#pragma unroll 1
        for (int l = 0; l < NLAYERS; ++l) {
            v8h wA0 = *(const v8h*)&wA_sh[l][0][lane][0];   // ds_read_b128
            v8h wA1 = *(const v8h*)&wA_sh[l][1][lane][0];   // ds_read_b128
            v4f bc0 = *(const v4f*)&bc_sh[l][0][4 * g];     // b128 broadcast
            v4f bc1 = *(const v4f*)&bc_sh[l][1][4 * g];

#pragma unroll
            for (int gr = 0; gr < NCHAIN / 2; ++gr) {
                const int c0 = 2 * gr, c1 = 2 * gr + 1;
                v4f a00 = __builtin_amdgcn_mfma_f32_16x16x32_f16(wA0, f[c0][0].v, bc0, 0, 0, 0);
                v4f a01 = __builtin_amdgcn_mfma_f32_16x16x32_f16(wA0, f[c0][1].v, bc0, 0, 0, 0);
                v4f a02 = __builtin_amdgcn_mfma_f32_16x16x32_f16(wA1, f[c0][0].v, bc1, 0, 0, 0);
                v4f a03 = __builtin_amdgcn_mfma_f32_16x16x32_f16(wA1, f[c0][1].v, bc1, 0, 0, 0);
                v4f a10 = __builtin_amdgcn_mfma_f32_16x16x32_f16(wA0, f[c1][0].v, bc0, 0, 0, 0);
                v4f a11 = __builtin_amdgcn_mfma_f32_16x16x32_f16(wA0, f[c1][1].v, bc0, 0, 0, 0);
                v4f a12 = __builtin_amdgcn_mfma_f32_16x16x32_f16(wA1, f[c1][0].v, bc1, 0, 0, 0);
                v4f a13 = __builtin_amdgcn_mfma_f32_16x16x32_f16(wA1, f[c1][1].v, bc1, 0, 0, 0);

                f[c0][0].p[0] = leaky2(pk_cvt(a00[0], a00[1]), slope2);
                f[c0][0].p[1] = leaky2(pk_cvt(a00[2], a00[3]), slope2);
                f[c0][0].p[2] = leaky2(pk_cvt(a02[0], a02[1]), slope2);
                f[c0][0].p[3] = leaky2(pk_cvt(a02[2], a02[3]), slope2);
                f[c0][1].p[0] = leaky2(pk_cvt(a01[0], a01[1]), slope2);
                f[c0][1].p[1] = leaky2(pk_cvt(a01[2], a01[3]), slope2);
                f[c0][1].p[2] = leaky2(pk_cvt(a03[0], a03[1]), slope2);
                f[c0][1].p[3] = leaky2(pk_cvt(a03[2], a03[3]), slope2);
                f[c1][0].p[0] = leaky2(pk_cvt(a10[0], a10[1]), slope2);
                f[c1][0].p[1] = leaky2(pk_cvt(a10[2], a10[3]), slope2);
                f[c1][0].p[2] = leaky2(pk_cvt(a12[0], a12[1]), slope2);
                f[c1][0].p[3] = leaky2(pk_cvt(a12[2], a12[3]), slope2);
                f[c1][1].p[0] = leaky2(pk_cvt(a11[0], a11[1]), slope2);
                f[c1][1].p[1] = leaky2(pk_cvt(a11[2], a11[3]), slope2);
                f[c1][1].p[2] = leaky2(pk_cvt(a13[0], a13[1]), slope2);
                f[c1][1].p[3] = leaky2(pk_cvt(a13[2], a13[3]), slope2);
            }
        }

        // ---- output layer: fdot2, 4-group shuffle reduce, store ----
        {
            const v2h* wo = &wout_sh[g][0];
#pragma unroll
            for (int c = 0; c < NCHAIN; ++c)
#pragma unroll
                for (int nh = 0; nh < 2; ++nh) {
                    float p = 0.0f;
#pragma unroll
                    for (int jj = 0; jj < 4; ++jj)
                        p = __builtin_amdgcn_fdot2(f[c][nh].p[jj], wo[jj], p, false);
                    p += __shfl_xor(p, 16, 64);
                    p += __shfl_xor(p, 32, 64);   // sum over all 4 k-groups
                    // 8 (c,nh) combos, 2 per 16-lane group (coalesced 64B)
                    if (((2 * c + nh) & 3) == g) {
                        int idx = it * (NCHAIN * 32) + c * 32 + 16 * nh + col;
                        out[idx] = p + bo;
                    }
                }
        }

#pragma unroll
        for (int c = 0; c < NCHAIN; ++c) xc2[c] = xn2[c];
    }
}

extern "C" void kernel_launch(void* const* d_in, const int* in_sizes, int n_in,
                              void* d_out, int out_size, void* d_ws, size_t ws_size,
                              hipStream_t stream) {
    const float* x     = (const float*)d_in[0];
    const float* W_in  = (const float*)d_in[1];
    const float* b_in  = (const float*)d_in[2];
    const float* W_hid = (const float*)d_in[3];
    const float* b_hid = (const float*)d_in[4];
    const float* W_out = (const float*)d_in[5];
    const float* b_out = (const float*)d_in[6];
    float* out = (float*)d_out;

    int N = in_sizes[0];
    // 1024 blocks x 4 waves = 4096 waves = 4 waves/SIMD (128-reg cap via
    // launch_bounds(256,4), est. usage ~104 -> 24 slack, no spill; LDS
    // 19.3 KiB x 4 blocks/CU = 77 KiB). niter = 8192 -> exactly 2
    // iterations/wave; balanced LDS (~8us/CU) + latency coverage (~180%).
    dim3 block(256);
    dim3 grid(1024);
    mlp_mfma_kernel<<<grid, block, 0, stream>>>(x, W_in, b_in, W_hid, b_hid,
                                                W_out, b_out, out, N);
}